// Round 19
// baseline (156.649 us; speedup 1.0000x reference)
//
#include <hip/hip_runtime.h>
#include <hip/hip_bf16.h>
#include <stdint.h>

// MoE (E=16, D=1024, H=2048, K=2, T=2048), routed bf16-MFMA.
// R19 = R18 (best: 142-143us) with BN 64->128 at BK=64: per-CU K-step
// rounds drop 22.7 -> 17 (cost model: time = rounds x C, C latency-dominated
// and per-step-work-independent; validated R8/R9/R11/R12/R13). Per K-step a
// wave now does 32 MFMA + 12 vmem ops; LDS 66KB -> 2 blocks/CU.

#define E_ 16
#define D_ 1024
#define H_ 2048
#define K_ 2
#define T_ 2048
#define NP_ (T_ * K_)     // 4096 token-expert pairs
#define MTS_ 48           // max M-tiles: sum ceil(ne/128) <= 48

using short8 = __attribute__((ext_vector_type(8))) short;
using f32x4  = __attribute__((ext_vector_type(4))) float;

__device__ __forceinline__ unsigned short f2bf(float f) {
  union { float f; unsigned u; } x; x.f = f;
  unsigned r = x.u + 0x7fffu + ((x.u >> 16) & 1u);   // RNE
  return (unsigned short)(r >> 16);
}

// gelu(tanh approx) = x * sigmoid(1.595769...*(x + 0.044715 x^3))
__device__ __forceinline__ float gelu_f(float x) {
  float u = 1.5957691216057308f * (x + 0.044715f * x * x * x);
  return x / (1.f + __expf(-u));
}

__device__ __forceinline__ void waitv12() {
  asm volatile("s_waitcnt vmcnt(12)" ::: "memory");
  __builtin_amdgcn_sched_barrier(0);
}
__device__ __forceinline__ void waitv0() {
  asm volatile("s_waitcnt vmcnt(0)" ::: "memory");
  __builtin_amdgcn_sched_barrier(0);
}
__device__ __forceinline__ void barrier_only() {
  __builtin_amdgcn_sched_barrier(0);
  __builtin_amdgcn_s_barrier();
  __builtin_amdgcn_sched_barrier(0);
}
__device__ __forceinline__ void lgkm0_barrier() {
  asm volatile("s_waitcnt lgkmcnt(0)" ::: "memory");
  __builtin_amdgcn_sched_barrier(0);
  __builtin_amdgcn_s_barrier();
  __builtin_amdgcn_sched_barrier(0);
}

// Merged prep: block 0 = routing (256 threads); blocks 1..512 = inp->bf16.
__global__ void prep_kernel(const float* __restrict__ inp,
                            unsigned short* __restrict__ xb,
                            const int* __restrict__ gidx,
                            int* __restrict__ rows,
                            int* __restrict__ offsets,
                            int2* __restrict__ tiles) {
  if (blockIdx.x == 0) {
    __shared__ int cnt[E_], cur[E_];
    int tid = threadIdx.x;
    if (tid < E_) cnt[tid] = 0;
    __syncthreads();
    for (int p = tid; p < NP_; p += 256) atomicAdd(&cnt[gidx[p]], 1);
    __syncthreads();
    if (tid == 0) {
      int acc = 0;
      for (int e = 0; e < E_; ++e) { offsets[e] = acc; cur[e] = acc; acc += cnt[e]; }
      offsets[E_] = acc;
      int k = 0;
      for (int e = 0; e < E_; ++e)
        for (int m = offsets[e]; m < offsets[e] + cnt[e]; m += 128)
          tiles[k++] = make_int2(e, m);
      for (; k < MTS_; ++k) tiles[k] = make_int2(-1, 0);
    }
    __syncthreads();
    for (int p = tid; p < NP_; p += 256) {
      int e = gidx[p];
      int pos = atomicAdd(&cur[e], 1);
      rows[pos] = p;
    }
  } else {
    const int n4 = T_ * D_ / 4;
    const int stride = (gridDim.x - 1) * blockDim.x;
    for (int i = (blockIdx.x - 1) * blockDim.x + threadIdx.x; i < n4; i += stride) {
      float4 v = reinterpret_cast<const float4*>(inp)[i];
      ushort4 o = make_ushort4(f2bf(v.x), f2bf(v.y), f2bf(v.z), f2bf(v.w));
      reinterpret_cast<ushort4*>(xb)[i] = o;
    }
  }
}

#define GLOAD16(g, l)                                                        \
  __builtin_amdgcn_global_load_lds(                                          \
      (const __attribute__((address_space(1))) unsigned int*)(const void*)(g), \
      (__attribute__((address_space(3))) unsigned int*)(void*)(l), 16, 0, 0)

// NT GEMM: 128(M)x128(N)x64(K) tile, 4 waves as 2x2 (each 64x64).
// A (bf16) via global_load_lds, source-side XOR swizzle (verified R2-R18).
// B (f32) reg-staged full-line (8 lines/wave-instr), cvt bf16, ds_write
// XOR-swizzled (R9-verified mapping).
template<bool IS1>
__global__ __launch_bounds__(256, 2)
void moe_gemm(const unsigned short* __restrict__ A0,   // xb (IS1) or h
              const float* __restrict__ W,             // w1 or w2 (f32)
              const float* __restrict__ bias,          // b1 or b2  [E][NN]
              const int* __restrict__ rows,
              const int* __restrict__ offsets,
              const int2* __restrict__ tiles,
              const float* __restrict__ score,         // [T*K]
              unsigned short* __restrict__ Hout,       // h (IS1)
              float* __restrict__ Yout)                // y (!IS1)
{
  constexpr int BM = 128, BN = 128, BK = 64;
  constexpr int KD = IS1 ? D_ : H_;   // contraction dim
  constexpr int NN = IS1 ? H_ : D_;   // output cols
  constexpr int NT = KD / BK;         // 16 or 32 (even)

  const int2 tile = tiles[blockIdx.y];
  const int e = tile.x;
  if (e < 0) return;
  const int s0   = tile.y;
  const int send = offsets[e + 1];
  const int n0   = blockIdx.x * BN;

  __shared__ unsigned short As[2][BM][BK];   // XOR-slot swizzled
  __shared__ unsigned short Bs[2][BN][BK];   // XOR-slot swizzled
  __shared__ int rowsrc[BM];
  __shared__ int rowdst[BM];

  const int tid  = threadIdx.x;
  const int lane = tid & 63;
  const int wid  = tid >> 6;

  if (tid < BM) {
    int s = s0 + tid;
    bool v = s < send;
    int sc2 = v ? s : s0;
    if (IS1) {
      rowsrc[tid] = rows[sc2] >> 1;   // token id (K_=2)
      rowdst[tid] = v ? s : -1;       // h row (routed order)
    } else {
      rowsrc[tid] = sc2;              // h row
      rowdst[tid] = v ? rows[s] : -1; // pair id for scatter + score
    }
  }
  __syncthreads();

  // A staging: per wave 4 x global_load_lds(16B), 8 rows each; LDS dest
  // linear, SOURCE slot pre-XOR'd: LDS[row][s] holds global slot s^(row&7).
  const int arow  = lane >> 3;
  const int aslot = (lane & 7) ^ arow;
  const unsigned short* gA[4];
#pragma unroll
  for (int i = 0; i < 4; ++i)
    gA[i] = A0 + (size_t)rowsrc[wid * 32 + i * 8 + arow] * KD + aslot * 8;

  // B staging, line-efficient: thread t -> row t>>3 (0..31) + 32p, oct t&7.
  // Per (p,h) wave-instr: 8 consecutive rows x 128B contiguous = 8 full lines.
  const int brow = tid >> 3, boct = tid & 7;
  const float* gB0 = W + (size_t)e * NN * KD + (size_t)(n0 + brow) * KD + boct * 4;

  const int wr = wid >> 1, wc = wid & 1;
  const int fr = lane & 15, fh = lane >> 4;

  f32x4 acc[4][4] = {};
  float4 breg0[8], breg1[8];

  auto issueA = [&](int buf, int kk) {
#pragma unroll
    for (int i = 0; i < 4; ++i)
      GLOAD16(gA[i] + kk, &As[buf][wid * 32 + i * 8][0]);
  };
  auto issueB = [&](float4* br, int kk) {
#pragma unroll
    for (int p = 0; p < 4; ++p) {
#pragma unroll
      for (int h = 0; h < 2; ++h)
        br[p * 2 + h] = *reinterpret_cast<const float4*>(
            gB0 + (size_t)p * 32 * KD + kk + h * 32);
    }
  };
  // piece (row, kl0): 4 shorts at swizzled addr; slot=(kl0>>3)^(row&7).
  auto writeB = [&](int buf, const float4* br) {
#pragma unroll
    for (int p = 0; p < 4; ++p) {
#pragma unroll
      for (int h = 0; h < 2; ++h) {
        int row = brow + p * 32;
        int kl0 = boct * 4 + h * 32;
        ushort4 u;
        const float* f = &br[p * 2 + h].x;
        u.x = f2bf(f[0]); u.y = f2bf(f[1]); u.z = f2bf(f[2]); u.w = f2bf(f[3]);
        int idx = (((kl0 >> 3) ^ (row & 7)) << 3) + (kl0 & 7);
        *reinterpret_cast<ushort4*>(&Bs[buf][row][idx]) = u;
      }
    }
  };
  auto compute = [&](int buf) {
#pragma unroll
    for (int ks = 0; ks < 2; ++ks) {
      short8 af[4], bv[4];
#pragma unroll
      for (int mi = 0; mi < 4; ++mi) {
        const int row = wr * 64 + mi * 16 + fr;
        const int slot = (ks * 4 + fh) ^ (row & 7);
        af[mi] = *reinterpret_cast<const short8*>(&As[buf][row][slot * 8]);
      }
#pragma unroll
      for (int ni = 0; ni < 4; ++ni) {
        const int row = wc * 64 + ni * 16 + fr;
        const int slot = (ks * 4 + fh) ^ (row & 7);
        bv[ni] = *reinterpret_cast<const short8*>(&Bs[buf][row][slot * 8]);
      }
#pragma unroll
      for (int mi = 0; mi < 4; ++mi)
#pragma unroll
        for (int ni = 0; ni < 4; ++ni)
          acc[mi][ni] = __builtin_amdgcn_mfma_f32_16x16x32_bf16(
              af[mi], bv[ni], acc[mi][ni], 0, 0, 0);
    }
  };

  // Prologue: issue tiles 0,1 (24 vmem ops/wave), land tile 0.
  issueA(0, 0);       issueB(breg0, 0);
  issueA(1, BK);      issueB(breg1, BK);
  waitv12();                      // tile-0 ops (oldest 12) complete
  writeB(0, breg0);
  lgkm0_barrier();                // all waves: tile 0 fully in LDS

  for (int t = 0; t < NT; t += 2) {
    // ---- step t (buffers 0) ----
    compute(0);
    barrier_only();               // all waves done reading LDS[0]
    if (t + 2 < NT) {
      issueA(0, (t + 2) * BK); issueB(breg0, (t + 2) * BK);
      waitv12();                  // {t+1} ops complete
    } else {
      waitv0();
    }
    writeB(1, breg1);
    lgkm0_barrier();              // all waves: tile t+1 fully in LDS
    // ---- step t+1 (buffers 1) ----
    compute(1);
    barrier_only();               // all waves done reading LDS[1]
    if (t + 2 < NT) {
      if (t + 3 < NT) { issueA(1, (t + 3) * BK); issueB(breg1, (t + 3) * BK); waitv12(); }
      else            { waitv0(); }
      writeB(0, breg0);
      lgkm0_barrier();            // all waves: tile t+2 fully in LDS
    }
  }

  // Epilogue. C/D map: row = (lane>>4)*4 + j, col = lane&15 (m89-verified).
  const float* biasE = bias + (size_t)e * NN + n0;
#pragma unroll
  for (int mi = 0; mi < 4; ++mi) {
#pragma unroll
    for (int j = 0; j < 4; ++j) {
      int rt  = wr * 64 + mi * 16 + fh * 4 + j;
      int dst = rowdst[rt];
      if (dst < 0) continue;
      float sc = IS1 ? 0.f : score[dst];
#pragma unroll
      for (int ni = 0; ni < 4; ++ni) {
        int col = wc * 64 + ni * 16 + fr;
        float v = acc[mi][ni][j] + biasE[col];
        if (IS1) {
          Hout[(size_t)dst * H_ + n0 + col] = f2bf(gelu_f(v));
        } else {
          Yout[(size_t)dst * D_ + n0 + col] = v * sc;
        }
      }
    }
  }
}

__global__ void combine_kernel(const float* __restrict__ y,
                               float* __restrict__ out) {
  const int DQ = D_ / 4;
  int i = blockIdx.x * blockDim.x + threadIdx.x;   // [0, T_*D_/4)
  int t = i / DQ, d = i % DQ;
  const float4* y4 = reinterpret_cast<const float4*>(y);
  float4 a = y4[(size_t)(2 * t) * DQ + d];
  float4 b = y4[(size_t)(2 * t + 1) * DQ + d];
  reinterpret_cast<float4*>(out)[i] =
      make_float4(a.x + b.x, a.y + b.y, a.z + b.z, a.w + b.w);
}

extern "C" void kernel_launch(void* const* d_in, const int* in_sizes, int n_in,
                              void* d_out, int out_size, void* d_ws, size_t ws_size,
                              hipStream_t stream) {
  const float* inp    = (const float*)d_in[0];
  const int*   gidx   = (const int*)d_in[1];
  const float* gscore = (const float*)d_in[2];
  const float* w1     = (const float*)d_in[3];
  const float* b1     = (const float*)d_in[4];
  const float* w2     = (const float*)d_in[5];
  const float* b2     = (const float*)d_in[6];
  float* out = (float*)d_out;

  char* ws = (char*)d_ws;
  size_t o = 0;
  auto alloc = [&](size_t bytes) {
    void* p = ws + o;
    o = (o + bytes + 255) & ~(size_t)255;
    return p;
  };
  unsigned short* xb   = (unsigned short*)alloc((size_t)T_ * D_ * 2);
  unsigned short* hbuf = (unsigned short*)alloc((size_t)NP_ * H_ * 2);
  float*          ybuf = (float*)alloc((size_t)NP_ * D_ * 4);
  int*            rows = (int*)alloc(NP_ * 4);
  int*         offsets = (int*)alloc((E_ + 1) * 4);
  int2*          tiles = (int2*)alloc(MTS_ * 8);

  prep_kernel<<<dim3(513), dim3(256), 0, stream>>>(inp, xb, gidx, rows,
                                                   offsets, tiles);

  moe_gemm<true><<<dim3(H_ / 128, MTS_), dim3(256), 0, stream>>>(
      xb, w1, b1, rows, offsets, tiles, gscore, hbuf, (float*)nullptr);
  moe_gemm<false><<<dim3(D_ / 128, MTS_), dim3(256), 0, stream>>>(
      hbuf, w2, b2, rows, offsets, tiles, gscore, (unsigned short*)nullptr, ybuf);

  combine_kernel<<<dim3(T_ * D_ / 4 / 256), dim3(256), 0, stream>>>(ybuf, out);
}

// Round 20
// 141.736 us; speedup vs baseline: 1.1052x; 1.1052x over previous
//
#include <hip/hip_runtime.h>
#include <hip/hip_bf16.h>
#include <stdint.h>

// MoE (E=16, D=1024, H=2048, K=2, T=2048), routed bf16-MFMA.
// R20 = R16/R18 verbatim — the measured best (142.4 / 143.1 us, reproduced
// twice). Final configuration after 19 rounds of falsification:
//   prep (block 0 routes token-expert pairs into per-expert slot ranges +
//   builds the compact 48-entry M-tile table; blocks 1..512 convert inp to
//   bf16) -> GEMM1 (gathered A, fused bias+gelu, h in routed order) ->
//   GEMM2 (contiguous A, fused bias+gate-score, scatter y by pair) ->
//   combine (out[t] = y[2t] + y[2t+1]).
// GEMM: 128x64x64 tile, 4 waves 2x2, A bf16 via global_load_lds (source
// XOR swizzle, conflict-free), B f32 reg-staged full-cache-line loads ->
// cvt bf16 -> ds_write XOR-swizzled, counted vmcnt(8) double-buffer,
// 49KB LDS -> 3 blocks/CU. Levers tested and rejected: deeper pipeline
// (R8), higher occupancy (R11), fewer barriers (R12/R13), all-linear
// streams (R7/R10), split-K (R13), producer-consumer fusion (R14),
// persistent work-stealing (R15), XCD remap (R17), BN=128 (R19).

#define E_ 16
#define D_ 1024
#define H_ 2048
#define K_ 2
#define T_ 2048
#define NP_ (T_ * K_)     // 4096 token-expert pairs
#define MTS_ 48           // max M-tiles: sum ceil(ne/128) <= 48

using short8 = __attribute__((ext_vector_type(8))) short;
using f32x4  = __attribute__((ext_vector_type(4))) float;

__device__ __forceinline__ unsigned short f2bf(float f) {
  union { float f; unsigned u; } x; x.f = f;
  unsigned r = x.u + 0x7fffu + ((x.u >> 16) & 1u);   // RNE
  return (unsigned short)(r >> 16);
}

// gelu(tanh approx) = x * sigmoid(1.595769...*(x + 0.044715 x^3))
__device__ __forceinline__ float gelu_f(float x) {
  float u = 1.5957691216057308f * (x + 0.044715f * x * x * x);
  return x / (1.f + __expf(-u));
}

__device__ __forceinline__ void waitv8() {
  asm volatile("s_waitcnt vmcnt(8)" ::: "memory");
  __builtin_amdgcn_sched_barrier(0);
}
__device__ __forceinline__ void waitv0() {
  asm volatile("s_waitcnt vmcnt(0)" ::: "memory");
  __builtin_amdgcn_sched_barrier(0);
}
__device__ __forceinline__ void barrier_only() {
  __builtin_amdgcn_sched_barrier(0);
  __builtin_amdgcn_s_barrier();
  __builtin_amdgcn_sched_barrier(0);
}
__device__ __forceinline__ void lgkm0_barrier() {
  asm volatile("s_waitcnt lgkmcnt(0)" ::: "memory");
  __builtin_amdgcn_sched_barrier(0);
  __builtin_amdgcn_s_barrier();
  __builtin_amdgcn_sched_barrier(0);
}

// Merged prep: block 0 = routing (256 threads); blocks 1..512 = inp->bf16.
__global__ void prep_kernel(const float* __restrict__ inp,
                            unsigned short* __restrict__ xb,
                            const int* __restrict__ gidx,
                            int* __restrict__ rows,
                            int* __restrict__ offsets,
                            int2* __restrict__ tiles) {
  if (blockIdx.x == 0) {
    __shared__ int cnt[E_], cur[E_];
    int tid = threadIdx.x;
    if (tid < E_) cnt[tid] = 0;
    __syncthreads();
    for (int p = tid; p < NP_; p += 256) atomicAdd(&cnt[gidx[p]], 1);
    __syncthreads();
    if (tid == 0) {
      int acc = 0;
      for (int e = 0; e < E_; ++e) { offsets[e] = acc; cur[e] = acc; acc += cnt[e]; }
      offsets[E_] = acc;
      int k = 0;
      for (int e = 0; e < E_; ++e)
        for (int m = offsets[e]; m < offsets[e] + cnt[e]; m += 128)
          tiles[k++] = make_int2(e, m);
      for (; k < MTS_; ++k) tiles[k] = make_int2(-1, 0);
    }
    __syncthreads();
    for (int p = tid; p < NP_; p += 256) {
      int e = gidx[p];
      int pos = atomicAdd(&cur[e], 1);
      rows[pos] = p;
    }
  } else {
    const int n4 = T_ * D_ / 4;
    const int stride = (gridDim.x - 1) * blockDim.x;
    for (int i = (blockIdx.x - 1) * blockDim.x + threadIdx.x; i < n4; i += stride) {
      float4 v = reinterpret_cast<const float4*>(inp)[i];
      ushort4 o = make_ushort4(f2bf(v.x), f2bf(v.y), f2bf(v.z), f2bf(v.w));
      reinterpret_cast<ushort4*>(xb)[i] = o;
    }
  }
}

#define GLOAD16(g, l)                                                        \
  __builtin_amdgcn_global_load_lds(                                          \
      (const __attribute__((address_space(1))) unsigned int*)(const void*)(g), \
      (__attribute__((address_space(3))) unsigned int*)(void*)(l), 16, 0, 0)

// NT GEMM: 128(M)x64(N)x64(K) tile, 4 waves as 2x2 (each 64x32).
// A (bf16) via global_load_lds, source-side XOR swizzle (verified R2-R18).
// B (f32) reg-staged line-efficient, cvt to bf16, ds_write XOR-swizzled.
template<bool IS1>
__global__ __launch_bounds__(256, 3)
void moe_gemm(const unsigned short* __restrict__ A0,   // xb (IS1) or h
              const float* __restrict__ W,             // w1 or w2 (f32)
              const float* __restrict__ bias,          // b1 or b2  [E][NN]
              const int* __restrict__ rows,
              const int* __restrict__ offsets,
              const int2* __restrict__ tiles,
              const float* __restrict__ score,         // [T*K]
              unsigned short* __restrict__ Hout,       // h (IS1)
              float* __restrict__ Yout)                // y (!IS1)
{
  constexpr int BM = 128, BN = 64, BK = 64;
  constexpr int KD = IS1 ? D_ : H_;   // contraction dim
  constexpr int NN = IS1 ? H_ : D_;   // output cols
  constexpr int NT = KD / BK;         // 16 or 32 (even)

  const int2 tile = tiles[blockIdx.y];
  const int e = tile.x;
  if (e < 0) return;
  const int s0   = tile.y;
  const int send = offsets[e + 1];
  const int n0   = blockIdx.x * BN;

  __shared__ unsigned short As[2][BM][BK];   // XOR-slot swizzled
  __shared__ unsigned short Bs[2][BN][BK];   // XOR-slot swizzled
  __shared__ int rowsrc[BM];
  __shared__ int rowdst[BM];

  const int tid  = threadIdx.x;
  const int lane = tid & 63;
  const int wid  = tid >> 6;

  if (tid < BM) {
    int s = s0 + tid;
    bool v = s < send;
    int sc2 = v ? s : s0;
    if (IS1) {
      rowsrc[tid] = rows[sc2] >> 1;   // token id (K_=2)
      rowdst[tid] = v ? s : -1;       // h row (routed order)
    } else {
      rowsrc[tid] = sc2;              // h row
      rowdst[tid] = v ? rows[s] : -1; // pair id for scatter + score
    }
  }
  __syncthreads();

  // A staging: per wave 4 x global_load_lds(16B), 8 rows each; LDS dest
  // linear, SOURCE slot pre-XOR'd: LDS[row][s] holds global slot s^(row&7).
  const int arow  = lane >> 3;
  const int aslot = (lane & 7) ^ arow;
  const unsigned short* gA[4];
#pragma unroll
  for (int i = 0; i < 4; ++i)
    gA[i] = A0 + (size_t)rowsrc[wid * 32 + i * 8 + arow] * KD + aslot * 8;

  // B staging, line-efficient: thread t -> row t>>3 (0..31), oct t&7.
  // Each wave-instr = 8 consecutive rows x 128B contiguous (8 full lines).
  const int brow = tid >> 3, boct = tid & 7;
  const float* gB0 = W + (size_t)e * NN * KD + (size_t)(n0 + brow) * KD + boct * 4;
  const float* gB2 = gB0 + (size_t)32 * KD;

  const int wr = wid >> 1, wc = wid & 1;
  const int fr = lane & 15, fh = lane >> 4;

  f32x4 acc[4][2] = {};
  float4 breg0[4], breg1[4];

  auto issueA = [&](int buf, int kk) {
#pragma unroll
    for (int i = 0; i < 4; ++i)
      GLOAD16(gA[i] + kk, &As[buf][wid * 32 + i * 8][0]);
  };
  auto issueB = [&](float4* br, int kk) {
    br[0] = *reinterpret_cast<const float4*>(gB0 + kk);
    br[1] = *reinterpret_cast<const float4*>(gB0 + kk + 32);
    br[2] = *reinterpret_cast<const float4*>(gB2 + kk);
    br[3] = *reinterpret_cast<const float4*>(gB2 + kk + 32);
  };
  // piece (row, kl0): 4 shorts at swizzled addr; slot=(kl0>>3)^(row&7).
  auto writeB = [&](int buf, const float4* br) {
#pragma unroll
    for (int p = 0; p < 4; ++p) {
      int row = (p & 2) ? brow + 32 : brow;
      int kl0 = boct * 4 + ((p & 1) ? 32 : 0);
      ushort4 u;
      const float* f = &br[p].x;
      u.x = f2bf(f[0]); u.y = f2bf(f[1]); u.z = f2bf(f[2]); u.w = f2bf(f[3]);
      int idx = (((kl0 >> 3) ^ (row & 7)) << 3) + (kl0 & 7);
      *reinterpret_cast<ushort4*>(&Bs[buf][row][idx]) = u;
    }
  };
  auto compute = [&](int buf) {
    short8 af[4][2], bv[2][2];
#pragma unroll
    for (int mi = 0; mi < 4; ++mi) {
      const int row = wr * 64 + mi * 16 + fr;
#pragma unroll
      for (int ks = 0; ks < 2; ++ks) {
        const int slot = (ks * 4 + fh) ^ (row & 7);
        af[mi][ks] = *reinterpret_cast<const short8*>(&As[buf][row][slot * 8]);
      }
    }
#pragma unroll
    for (int ni = 0; ni < 2; ++ni) {
      const int row = wc * 32 + ni * 16 + fr;
#pragma unroll
      for (int ks = 0; ks < 2; ++ks) {
        const int slot = (ks * 4 + fh) ^ (row & 7);
        bv[ni][ks] = *reinterpret_cast<const short8*>(&Bs[buf][row][slot * 8]);
      }
    }
#pragma unroll
    for (int ks = 0; ks < 2; ++ks)
#pragma unroll
      for (int mi = 0; mi < 4; ++mi)
#pragma unroll
        for (int ni = 0; ni < 2; ++ni)
          acc[mi][ni] = __builtin_amdgcn_mfma_f32_16x16x32_bf16(
              af[mi][ks], bv[ni][ks], acc[mi][ni], 0, 0, 0);
  };

  // Prologue: issue tiles 0,1 (16 vmem ops/wave), land tile 0.
  issueA(0, 0);       issueB(breg0, 0);
  issueA(1, BK);      issueB(breg1, BK);
  waitv8();                       // tile-0 ops (oldest 8) complete
  writeB(0, breg0);
  lgkm0_barrier();                // all waves: tile 0 fully in LDS

  for (int t = 0; t < NT; t += 2) {
    // ---- step t (buffers 0) ----
    compute(0);
    barrier_only();               // all waves done reading LDS[0]
    if (t + 2 < NT) {
      issueA(0, (t + 2) * BK); issueB(breg0, (t + 2) * BK);
      waitv8();                   // {t+1} ops complete
    } else {
      waitv0();
    }
    writeB(1, breg1);
    lgkm0_barrier();              // all waves: tile t+1 fully in LDS
    // ---- step t+1 (buffers 1) ----
    compute(1);
    barrier_only();               // all waves done reading LDS[1]
    if (t + 2 < NT) {
      if (t + 3 < NT) { issueA(1, (t + 3) * BK); issueB(breg1, (t + 3) * BK); waitv8(); }
      else            { waitv0(); }
      writeB(0, breg0);
      lgkm0_barrier();            // all waves: tile t+2 fully in LDS
    }
  }

  // Epilogue. C/D map: row = (lane>>4)*4 + j, col = lane&15 (m89-verified).
  const float* biasE = bias + (size_t)e * NN + n0;
#pragma unroll
  for (int mi = 0; mi < 4; ++mi) {
#pragma unroll
    for (int j = 0; j < 4; ++j) {
      int rt  = wr * 64 + mi * 16 + fh * 4 + j;
      int dst = rowdst[rt];
      if (dst < 0) continue;
      float sc = IS1 ? 0.f : score[dst];
#pragma unroll
      for (int ni = 0; ni < 2; ++ni) {
        int col = wc * 32 + ni * 16 + fr;
        float v = acc[mi][ni][j] + biasE[col];
        if (IS1) {
          Hout[(size_t)dst * H_ + n0 + col] = f2bf(gelu_f(v));
        } else {
          Yout[(size_t)dst * D_ + n0 + col] = v * sc;
        }
      }
    }
  }
}

__global__ void combine_kernel(const float* __restrict__ y,
                               float* __restrict__ out) {
  const int DQ = D_ / 4;
  int i = blockIdx.x * blockDim.x + threadIdx.x;   // [0, T_*D_/4)
  int t = i / DQ, d = i % DQ;
  const float4* y4 = reinterpret_cast<const float4*>(y);
  float4 a = y4[(size_t)(2 * t) * DQ + d];
  float4 b = y4[(size_t)(2 * t + 1) * DQ + d];
  reinterpret_cast<float4*>(out)[i] =
      make_float4(a.x + b.x, a.y + b.y, a.z + b.z, a.w + b.w);
}

extern "C" void kernel_launch(void* const* d_in, const int* in_sizes, int n_in,
                              void* d_out, int out_size, void* d_ws, size_t ws_size,
                              hipStream_t stream) {
  const float* inp    = (const float*)d_in[0];
  const int*   gidx   = (const int*)d_in[1];
  const float* gscore = (const float*)d_in[2];
  const float* w1     = (const float*)d_in[3];
  const float* b1     = (const float*)d_in[4];
  const float* w2     = (const float*)d_in[5];
  const float* b2     = (const float*)d_in[6];
  float* out = (float*)d_out;

  char* ws = (char*)d_ws;
  size_t o = 0;
  auto alloc = [&](size_t bytes) {
    void* p = ws + o;
    o = (o + bytes + 255) & ~(size_t)255;
    return p;
  };
  unsigned short* xb   = (unsigned short*)alloc((size_t)T_ * D_ * 2);
  unsigned short* hbuf = (unsigned short*)alloc((size_t)NP_ * H_ * 2);
  float*          ybuf = (float*)alloc((size_t)NP_ * D_ * 4);
  int*            rows = (int*)alloc(NP_ * 4);
  int*         offsets = (int*)alloc((E_ + 1) * 4);
  int2*          tiles = (int2*)alloc(MTS_ * 8);

  prep_kernel<<<dim3(513), dim3(256), 0, stream>>>(inp, xb, gidx, rows,
                                                   offsets, tiles);

  moe_gemm<true><<<dim3(H_ / 64, MTS_), dim3(256), 0, stream>>>(
      xb, w1, b1, rows, offsets, tiles, gscore, hbuf, (float*)nullptr);
  moe_gemm<false><<<dim3(D_ / 64, MTS_), dim3(256), 0, stream>>>(
      hbuf, w2, b2, rows, offsets, tiles, gscore, (unsigned short*)nullptr, ybuf);

  combine_kernel<<<dim3(T_ * D_ / 4 / 256), dim3(256), 0, stream>>>(ybuf, out);
}